// Round 15
// baseline (1745.402 us; speedup 1.0000x reference)
//
#include <hip/hip_runtime.h>

#define NSTEP 2048

typedef __attribute__((ext_vector_type(8))) short short8;
typedef __attribute__((ext_vector_type(4))) float f32x4;
typedef __attribute__((ext_vector_type(4))) int i32x4;

static __device__ __forceinline__ unsigned short f2bf(float f){
  unsigned u = __builtin_bit_cast(unsigned, f);
  u += 0x7FFFu + ((u >> 16) & 1u);   // RNE
  return (unsigned short)(u >> 16);
}

// ---------------- fp32 -> bf16 (for W_ih) ----------------
__global__ __launch_bounds__(256,1)
void cvt_bf16_k(const float* __restrict__ in, unsigned short* __restrict__ out, int n4){
  int i = blockIdx.x*256 + threadIdx.x;
  if (i < n4){
    f32x4 v = *(const f32x4*)(in + (size_t)i*4);
    ushort4 o; o.x=f2bf(v.x); o.y=f2bf(v.y); o.z=f2bf(v.z); o.w=f2bf(v.w);
    *(ushort4*)(out + (size_t)i*4) = o;
  }
}

// ---------------- phase-1: xp for m-tiles 0..31 (rows 0..4095, s<256) ----------------
__global__ __launch_bounds__(256,1)
void gemm_head_k(const float* __restrict__ X, const unsigned short* __restrict__ Wb,
                 const float* __restrict__ bih, const float* __restrict__ bhh,
                 float* __restrict__ XP){
  __shared__ __align__(16) unsigned short sA[128*40];
  __shared__ __align__(16) unsigned short sB[128*40];
  const float NL2E  = -1.4426950408889634f;
  const float NL2E2 = -2.8853900817779268f;
  int bid = blockIdx.x;
  int mt = bid / 6, nt = bid % 6;             // mt 0..31
  int m0 = mt*128, n0 = nt*128;
  int tid = threadIdx.x;
  int lane = tid & 63, wave = tid >> 6;
  int wm = wave >> 1, wn = wave & 1;
  int rA = lane & 15, kg = lane >> 4;
  f32x4 acc[4][4] = {};
  for (int k0 = 0; k0 < 1024; k0 += 32){
    __syncthreads();
    #pragma unroll
    for (int q = 0; q < 4; q++){
      int idx = tid + q*256;
      int r = idx >> 3, c4 = idx & 7;
      f32x4 v = *(const f32x4*)(X + (size_t)(m0+r)*1024 + k0 + c4*4);
      ushort4 o; o.x=f2bf(v.x); o.y=f2bf(v.y); o.z=f2bf(v.z); o.w=f2bf(v.w);
      *(ushort4*)&sA[r*40 + c4*4] = o;
    }
    #pragma unroll
    for (int q = 0; q < 2; q++){
      int idx = tid + q*256;
      int n = idx >> 2, c8 = idx & 3;
      uint4 v = *(const uint4*)(Wb + (size_t)(n0+n)*1024 + k0 + c8*8);
      *(uint4*)&sB[n*40 + c8*8] = v;
    }
    __syncthreads();
    short8 af[4], bf[4];
    #pragma unroll
    for (int i=0;i<4;i++) af[i] = *(const short8*)&sA[(wm*64 + 16*i + rA)*40 + kg*8];
    #pragma unroll
    for (int j=0;j<4;j++) bf[j] = *(const short8*)&sB[(wn*64 + 16*j + rA)*40 + kg*8];
    #pragma unroll
    for (int i=0;i<4;i++)
      #pragma unroll
      for (int j=0;j<4;j++)
        acc[i][j] = __builtin_amdgcn_mfma_f32_16x16x32_bf16(af[i], bf[j], acc[i][j], 0, 0, 0);
  }
  #pragma unroll
  for (int i=0;i<4;i++){
    int rb = m0 + wm*64 + 16*i + kg*4;
    #pragma unroll
    for (int j=0;j<4;j++){
      int cc = n0 + wn*64 + 16*j + rA;
      float bv = bih[cc] + bhh[cc];
      float sc = (cc < 512) ? NL2E : NL2E2;
      #pragma unroll
      for (int rg=0;rg<4;rg++)
        XP[(size_t)(rb+rg)*768 + cc] = (acc[i][j][rg] + bv) * sc;
    }
  }
}

// ---------------- fused: gru (blocks 0..15) + gemm m-tiles 32..255 (blocks 16..1359) ----
// CU EXCLUSIVITY via a SINGLE 84480B static LDS object that is GENUINELY USED at both
// ends (sA/sB staging at offsets 0/10240, h_q at 83968): runtime-indexed reads/writes
// make it un-eliminable, so the group segment is 84480B > 160KB/2 -> exactly ONE block
// per CU by the kernel descriptor. (R13's dynamic pad was dropped at dispatch; R14's
// guarded store was DCE'd — LDS_Block_Size stayed 20992 both times, so the hypothesis
// never ran.) gru blocks 0..15 land in the first dispatch wave and own 16 CUs outright;
// gemm blocks cycle 1-per-CU over the other 240. Handshake unchanged (3x validated).
__global__ __launch_bounds__(512,2)
void fused_k(const float* __restrict__ xp_c, float* __restrict__ XP,
             const float* __restrict__ X, const unsigned short* __restrict__ Wb,
             const float* __restrict__ bih, const float* __restrict__ bhh,
             const float* __restrict__ Whh, char* __restrict__ hs8,
             int* prog, int* wgcnt, int* done){
  __shared__ __align__(16) char lds_all[84480];         // > 81920 -> 1 block/CU
  unsigned short* sA = (unsigned short*)lds_all;        // 128*40*2 = 10240 B
  unsigned short* sB = (unsigned short*)(lds_all + 10240); // 10240 B
  char* h_q = lds_all + 83968;                          // 2*256 = 512 B at array end

  const float NL2E  = -1.4426950408889634f;
  const float NL2E2 = -2.8853900817779268f;
  int tid = threadIdx.x;
  int lane = tid & 63, wave = tid >> 6;
  int rA = lane & 15, kg = lane >> 4;

  if (blockIdx.x >= 16){
    // ================= gemm part: 512 threads, tile 128x128, BK=32 =================
    int gbid = blockIdx.x - 16;
    int mt = 32 + gbid / 6, nt = gbid % 6;
    int m0 = mt*128, n0 = nt*128;
    int wm = wave >> 1, wn = wave & 1;        // 4x2 wave grid: 32-row x 64-col per wave
    f32x4 acc[2][4] = {};
    for (int k0 = 0; k0 < 1024; k0 += 32){
      __syncthreads();
      #pragma unroll
      for (int q = 0; q < 2; q++){           // A: 128x32 fp32->bf16
        int idx = tid + q*512;
        int r = idx >> 3, c4 = idx & 7;
        f32x4 v = *(const f32x4*)(X + (size_t)(m0+r)*1024 + k0 + c4*4);
        ushort4 o; o.x=f2bf(v.x); o.y=f2bf(v.y); o.z=f2bf(v.z); o.w=f2bf(v.w);
        *(ushort4*)&sA[r*40 + c4*4] = o;
      }
      {                                       // B: 128x32 bf16
        int n = tid >> 2, c8 = tid & 3;
        uint4 v = *(const uint4*)(Wb + (size_t)(n0+n)*1024 + k0 + c8*8);
        *(uint4*)&sB[n*40 + c8*8] = v;
      }
      __syncthreads();
      short8 af[2], bf[4];
      #pragma unroll
      for (int i=0;i<2;i++) af[i] = *(const short8*)&sA[(wm*32 + 16*i + rA)*40 + kg*8];
      #pragma unroll
      for (int j=0;j<4;j++) bf[j] = *(const short8*)&sB[(wn*64 + 16*j + rA)*40 + kg*8];
      #pragma unroll
      for (int i=0;i<2;i++)
        #pragma unroll
        for (int j=0;j<4;j++)
          acc[i][j] = __builtin_amdgcn_mfma_f32_16x16x32_bf16(af[i], bf[j], acc[i][j], 0, 0, 0);
    }
    #pragma unroll
    for (int i=0;i<2;i++){
      int rb = m0 + wm*32 + 16*i + kg*4;
      #pragma unroll
      for (int j=0;j<4;j++){
        int cc = n0 + wn*64 + 16*j + rA;
        float bv = bih[cc] + bhh[cc];
        float sc = (cc < 512) ? NL2E : NL2E2;
        #pragma unroll
        for (int rg=0;rg<4;rg++)
          XP[(size_t)(rb+rg)*768 + cc] = (acc[i][j][rg] + bv) * sc;
      }
    }
    __threadfence();                          // publish stores device-wide
    __syncthreads();
    if (tid == 0){
      __hip_atomic_fetch_add(&prog[mt], 1, __ATOMIC_RELEASE, __HIP_MEMORY_SCOPE_AGENT);
      int old = __hip_atomic_fetch_add(wgcnt, 1, __ATOMIC_ACQ_REL, __HIP_MEMORY_SCOPE_AGENT);
      if (old == 1343)
        __hip_atomic_store(done, 1, __ATOMIC_RELEASE, __HIP_MEMORY_SCOPE_AGENT);
    }
    return;
  }

  // ================= gru part (R11 structure, exclusive CU) =================
  int b = blockIdx.x;
  int ua = 32*wave + rA;                       // unit a; unit b = ua + 16
  const float* xp = xp_c;

  // ---- startup: per-row int8 quantization of W_hh into register B-fragments ----
  i32x4 bw[3][2][4];
  float dsc[3][2];                             // dequant scale, exp2 factor folded in
  #pragma unroll
  for (int g=0; g<3; g++){
    #pragma unroll
    for (int hh=0; hh<2; hh++){
      const float* rp = Whh + (size_t)(g*256 + 32*wave + hh*16 + rA)*256 + kg*16;
      float mx = 0.f;
      #pragma unroll
      for (int kk=0; kk<4; kk++)
        #pragma unroll
        for (int j=0; j<16; j++)
          mx = fmaxf(mx, fabsf(rp[kk*64 + j]));
      mx = fmaxf(mx, __shfl_xor(mx, 16, 64));  // reduce across kg groups (same rA)
      mx = fmaxf(mx, __shfl_xor(mx, 32, 64));
      mx = fmaxf(mx, 1e-20f);
      float s = 127.f / mx;
      float fold = (g == 2) ? NL2E2 : NL2E;
      dsc[g][hh] = mx * (1.f/(127.f*127.f)) * fold;
      #pragma unroll
      for (int kk=0; kk<4; kk++){
        i32x4 v;
        #pragma unroll
        for (int q=0; q<4; q++){
          const float* pp = rp + kk*64 + q*4;
          int q0 = __float2int_rn(pp[0]*s) & 255;
          int q1 = __float2int_rn(pp[1]*s) & 255;
          int q2 = __float2int_rn(pp[2]*s) & 255;
          int q3 = __float2int_rn(pp[3]*s) & 255;
          v[q] = q0 | (q1<<8) | (q2<<16) | (q3<<24);
        }
        bw[g][hh][kk] = v;
      }
    }
  }
  if (tid < 256) h_q[tid] = 0;                 // buffer 0 at h_q[0..255]
  __syncthreads();

  // ---- xp prefetch registers, depth 2 (XP prescaled; rows <4096 from phase-1) ----
  float xa[2][3], xb[2][3];
  {
    const float* q0 = xp + (size_t)b*768;
    const float* q1 = xp + (size_t)(16 + b)*768;
    #pragma unroll
    for (int g=0; g<3; g++){
      xa[0][g] = q0[g*256 + ua];  xb[0][g] = q0[g*256 + ua + 16];
      xa[1][g] = q1[g*256 + ua];  xb[1][g] = q1[g*256 + ua + 16];
    }
  }
  float ha = 0.f, hb = 0.f;                    // fp32 carried state (2 units/lane)
  const float* pA = xp + (size_t)(2*16 + b)*768 + ua;   // refill src (row T+2), +12288/half
  char* ph = hs8 + (size_t)b*256 + ua;                  // hs store, +4096/half
  bool all_done = false;

#define GRU_HALF(half, DO_REFILL)                                                        \
  {                                                                                      \
    i32x4 a[4];                                                                          \
    _Pragma("unroll")                                                                    \
    for (int kk=0; kk<4; kk++)                                                           \
      a[kk] = *(const i32x4*)&h_q[(half)*256 + kk*64 + kg*16];                           \
    i32x4 a00={}, a01={}, a10={}, a11={}, a20={}, a21={};                                \
    __builtin_amdgcn_s_setprio(1);                                                       \
    _Pragma("unroll")                                                                    \
    for (int kk=0; kk<4; kk++){                                                          \
      a00 = __builtin_amdgcn_mfma_i32_16x16x64_i8(a[kk], bw[0][0][kk], a00, 0,0,0);      \
      a01 = __builtin_amdgcn_mfma_i32_16x16x64_i8(a[kk], bw[0][1][kk], a01, 0,0,0);      \
      a10 = __builtin_amdgcn_mfma_i32_16x16x64_i8(a[kk], bw[1][0][kk], a10, 0,0,0);      \
      a11 = __builtin_amdgcn_mfma_i32_16x16x64_i8(a[kk], bw[1][1][kk], a11, 0,0,0);      \
      a20 = __builtin_amdgcn_mfma_i32_16x16x64_i8(a[kk], bw[2][0][kk], a20, 0,0,0);      \
      a21 = __builtin_amdgcn_mfma_i32_16x16x64_i8(a[kk], bw[2][1][kk], a21, 0,0,0);      \
    }                                                                                    \
    __builtin_amdgcn_s_setprio(0);                                                       \
    float ra = __builtin_amdgcn_rcpf(1.f + __builtin_amdgcn_exp2f(fmaf((float)a00[0], dsc[0][0], xa[half][0]))); \
    float rb = __builtin_amdgcn_rcpf(1.f + __builtin_amdgcn_exp2f(fmaf((float)a01[0], dsc[0][1], xb[half][0]))); \
    float za = __builtin_amdgcn_rcpf(1.f + __builtin_amdgcn_exp2f(fmaf((float)a10[0], dsc[1][0], xa[half][1]))); \
    float zb = __builtin_amdgcn_rcpf(1.f + __builtin_amdgcn_exp2f(fmaf((float)a11[0], dsc[1][1], xb[half][1]))); \
    float na = fmaf(2.f, __builtin_amdgcn_rcpf(1.f + __builtin_amdgcn_exp2f(             \
                 fmaf(ra, (float)a20[0]*dsc[2][0], xa[half][2]))), -1.f);                \
    float nb = fmaf(2.f, __builtin_amdgcn_rcpf(1.f + __builtin_amdgcn_exp2f(             \
                 fmaf(rb, (float)a21[0]*dsc[2][1], xb[half][2]))), -1.f);                \
    ha = fmaf(za, ha - na, na);                                                          \
    hb = fmaf(zb, hb - nb, nb);                                                          \
    int qa = __float2int_rn(ha*127.f), qb = __float2int_rn(hb*127.f);                    \
    if (kg == 0){                                                                        \
      h_q[((half)^1)*256 + ua]    = (char)qa;                                            \
      h_q[((half)^1)*256 + ua+16] = (char)qb;                                            \
    }                                                                                    \
    if (kg == 1){                                                                        \
      ph[0]  = (char)qa;                                                                 \
      ph[16] = (char)qb;                                                                 \
    }                                                                                    \
    ph += 4096;                                                                          \
    if (DO_REFILL){                                                                      \
      if (!all_done && (((T+2)&7) == 0) && ((T+2) >> 3) >= 32){                          \
        int sb = (T+2) >> 3;                                                             \
        if (__hip_atomic_load(done, __ATOMIC_ACQUIRE, __HIP_MEMORY_SCOPE_AGENT) != 0){   \
          all_done = true;                                                               \
        } else {                                                                         \
          while (__hip_atomic_load(&prog[sb], __ATOMIC_ACQUIRE,                          \
                                   __HIP_MEMORY_SCOPE_AGENT) < 6){}                      \
        }                                                                                \
      }                                                                                  \
      xa[half][0] = pA[0];  xa[half][1] = pA[256]; xa[half][2] = pA[512];                \
      xb[half][0] = pA[16]; xb[half][1] = pA[272]; xb[half][2] = pA[528];                \
      pA += 12288;                                                                       \
    }                                                                                    \
    __builtin_amdgcn_sched_barrier(0);                                                   \
    asm volatile("s_waitcnt lgkmcnt(0)" ::: "memory");                                   \
    __builtin_amdgcn_s_barrier();                                                        \
    __builtin_amdgcn_sched_barrier(0);                                                   \
  }

  for (int t = 0; t < NSTEP-2; t += 2){
    { int T = t;     GRU_HALF(0, 1) }
    { int T = t + 1; GRU_HALF(1, 1) }
  }
  { int T = NSTEP-2; GRU_HALF(0, 0) }
  { int T = NSTEP-1; GRU_HALF(1, 0) }
#undef GRU_HALF
}

// ---------------- head: relu(h) @ W_out^T + b_out, softmax, outputs, task bins ----------------
__global__ __launch_bounds__(256,1)
void head_k(const char* __restrict__ hs8, const float* __restrict__ Wout,
            const float* __restrict__ bout, const int* __restrict__ task,
            float* __restrict__ out, float* __restrict__ sums, float* __restrict__ counts){
  __shared__ float sW[1024];
  __shared__ float sbin[8], scnt[8];
  int tid = threadIdx.x;
  for (int i = tid; i < 1024; i += 256) sW[i] = Wout[i] * (1.f/127.f);
  if (tid < 8){ sbin[tid] = 0.f; scnt[tid] = 0.f; }
  __syncthreads();
  int rowi = blockIdx.x*256 + tid;   // 32768 rows total
  const uint4* hp = (const uint4*)(hs8 + (size_t)rowi*256);
  float l0 = bout[0], l1 = bout[1], l2 = bout[2], l3 = bout[3];
  #pragma unroll 4
  for (int c = 0; c < 16; c++){
    uint4 v = hp[c];
    uint arr[4] = {v.x, v.y, v.z, v.w};
    #pragma unroll
    for (int q = 0; q < 4; q++){
      uint w = arr[q];
      int k = c*16 + q*4;
      float h0 = (float)max((int)(char)(w      ), 0);
      float h1 = (float)max((int)(char)(w >>  8), 0);
      float h2 = (float)max((int)(char)(w >> 16), 0);
      float h3 = (float)max((int)(w) >> 24,       0);
      l0 = fmaf(h0, sW[k],     l0); l0 = fmaf(h1, sW[k+1],     l0);
      l0 = fmaf(h2, sW[k+2],   l0); l0 = fmaf(h3, sW[k+3],     l0);
      l1 = fmaf(h0, sW[256+k], l1); l1 = fmaf(h1, sW[257+k],   l1);
      l1 = fmaf(h2, sW[258+k], l1); l1 = fmaf(h3, sW[259+k],   l1);
      l2 = fmaf(h0, sW[512+k], l2); l2 = fmaf(h1, sW[513+k],   l2);
      l2 = fmaf(h2, sW[514+k], l2); l2 = fmaf(h3, sW[515+k],   l2);
      l3 = fmaf(h0, sW[768+k], l3); l3 = fmaf(h1, sW[769+k],   l3);
      l3 = fmaf(h2, sW[770+k], l3); l3 = fmaf(h3, sW[771+k],   l3);
    }
  }
  float mx = fmaxf(fmaxf(l0,l1), fmaxf(l2,l3));
  float e0 = __expf(l0-mx), e1 = __expf(l1-mx), e2 = __expf(l2-mx), e3 = __expf(l3-mx);
  float inv = 1.f/(e0+e1+e2+e3);
  float p0 = e0*inv, p1 = e1*inv, p2 = e2*inv, p3 = e3*inv;
  size_t o = (size_t)rowi*4;
  out[o+0]=p0; out[o+1]=p1; out[o+2]=p2; out[o+3]=p3;
  out[131072+o+0]=p0; out[131072+o+1]=p1; out[131072+o+2]=p2; out[131072+o+3]=p3;
  out[262144+o+0]=0.f; out[262144+o+1]=1.f; out[262144+o+2]=2.f; out[262144+o+3]=3.f;
  float loss = 256.f*p0 + 512.f*p1 + 1024.f*p2 + 2048.f*p3;
  int tk = task[rowi] & 7;
  atomicAdd(&sbin[tk], loss);
  atomicAdd(&scnt[tk], 1.f);
  __syncthreads();
  if (tid < 8){
    atomicAdd(&sums[tid], sbin[tid]);
    atomicAdd(&counts[tid], scnt[tid]);
  }
}

__global__ void fin_k(const float* __restrict__ sums, const float* __restrict__ counts,
                      float* __restrict__ o3){
  int i = threadIdx.x;
  if (i < 8){ float c = counts[i]; o3[i] = c > 0.f ? sums[i]/c : 0.f; }
}

extern "C" void kernel_launch(void* const* d_in, const int* in_sizes, int n_in,
                              void* d_out, int out_size, void* d_ws, size_t ws_size,
                              hipStream_t stream){
  const float* x    = (const float*)d_in[0];
  const int*   task = (const int*)d_in[1];
  const float* Wih  = (const float*)d_in[2];
  const float* Whh  = (const float*)d_in[3];
  const float* bih  = (const float*)d_in[4];
  const float* bhh  = (const float*)d_in[5];
  const float* Wout = (const float*)d_in[6];
  const float* bout = (const float*)d_in[7];
  float* out = (float*)d_out;
  char* ws = (char*)d_ws;
  unsigned short* wih_bf = (unsigned short*)ws;              // 1,572,864 B
  float* xp    = (float*)(ws + 1572864);                     // 100,663,296 B
  char* hs8    = (char*)(ws + 102236160);                    // 8,388,608 B (int8 h)
  float* sums  = (float*)(ws + 111149056);                   // 32 B
  float* counts= (float*)(ws + 111149088);                   // 32 B
  int* prog    = (int*)(ws + 111149120);                     // 1024 B (per-m-tile flags)
  int* wgcnt   = (int*)(ws + 111150144);                     // 4 B
  int* done    = (int*)(ws + 111150148);                     // 4 B

  hipMemsetAsync(sums, 0, 1100, stream);                     // sums..done zeroed

  cvt_bf16_k<<<768, 256, 0, stream>>>(Wih, wih_bf, 196608);
  gemm_head_k<<<192, 256, 0, stream>>>(x, wih_bf, bih, bhh, xp);
  fused_k<<<1360, 512, 0, stream>>>(xp, xp, x, wih_bf, bih, bhh, Whh, hs8,
                                    prog, wgcnt, done);
  head_k<<<128, 256, 0, stream>>>(hs8, Wout, bout, task, out, sums, counts);
  fin_k<<<1, 64, 0, stream>>>(sums, counts, out + 393216);
}

// Round 16
// 1401.342 us; speedup vs baseline: 1.2455x; 1.2455x over previous
//
#include <hip/hip_runtime.h>

#define NSTEP 2048

typedef __attribute__((ext_vector_type(8))) short short8;
typedef __attribute__((ext_vector_type(4))) float f32x4;
typedef __attribute__((ext_vector_type(4))) int i32x4;

static __device__ __forceinline__ unsigned short f2bf(float f){
  unsigned u = __builtin_bit_cast(unsigned, f);
  u += 0x7FFFu + ((u >> 16) & 1u);   // RNE
  return (unsigned short)(u >> 16);
}

static __device__ __forceinline__ short8 pack8(f32x4 lo, f32x4 hi){
  short8 r;
  r[0]=(short)f2bf(lo.x); r[1]=(short)f2bf(lo.y); r[2]=(short)f2bf(lo.z); r[3]=(short)f2bf(lo.w);
  r[4]=(short)f2bf(hi.x); r[5]=(short)f2bf(hi.y); r[6]=(short)f2bf(hi.z); r[7]=(short)f2bf(hi.w);
  return r;
}

// ---------------- xp = (x @ W_ih^T + b_ih + b_hh) * exp2-prescale ----------------
// Columns 0-511 (r,z) scaled by -log2(e); 512-767 (n) by -2log2(e). Scaling lives in
// the GEMM epilogue so the GRU refill stays raw loads (R8/R9 lesson). W_ih staged
// directly from fp32 with in-flight bf16 conversion (cvt kernel folded in; B panels
// are L2/L3-resident so the extra fp32 read is free).
__global__ __launch_bounds__(256,1)
void gemm_xp_k(const float* __restrict__ X, const float* __restrict__ Wih,
               const float* __restrict__ bih, const float* __restrict__ bhh,
               float* __restrict__ XP){
  __shared__ __align__(16) unsigned short sA[128*40];
  __shared__ __align__(16) unsigned short sB[128*40];
  const float NL2E  = -1.4426950408889634f;
  const float NL2E2 = -2.8853900817779268f;
  int bid = blockIdx.x;
  int xcd = bid & 7, loc = bid >> 3;          // 1536 = 8 * 192
  int mt = xcd*32 + loc/6;
  int nt = loc % 6;
  int m0 = mt*128, n0 = nt*128;
  int tid = threadIdx.x;
  int lane = tid & 63, wave = tid >> 6;
  int wm = wave >> 1, wn = wave & 1;
  int rA = lane & 15, kg = lane >> 4;
  f32x4 acc[4][4] = {};
  for (int k0 = 0; k0 < 1024; k0 += 32){
    __syncthreads();
    #pragma unroll
    for (int q = 0; q < 4; q++){             // A: 128x32 fp32 -> bf16
      int idx = tid + q*256;
      int r = idx >> 3, c4 = idx & 7;
      f32x4 v = *(const f32x4*)(X + (size_t)(m0+r)*1024 + k0 + c4*4);
      ushort4 o; o.x=f2bf(v.x); o.y=f2bf(v.y); o.z=f2bf(v.z); o.w=f2bf(v.w);
      *(ushort4*)&sA[r*40 + c4*4] = o;
    }
    #pragma unroll
    for (int q = 0; q < 2; q++){             // B: 128x32 fp32 -> bf16 (in-flight cvt)
      int idx = tid + q*256;
      int n = idx >> 2, c8 = idx & 3;
      const float* p = Wih + (size_t)(n0+n)*1024 + k0 + c8*8;
      f32x4 lo = *(const f32x4*)p;
      f32x4 hi = *(const f32x4*)(p+4);
      *(short8*)&sB[n*40 + c8*8] = pack8(lo, hi);
    }
    __syncthreads();
    short8 af[4], bf[4];
    #pragma unroll
    for (int i=0;i<4;i++) af[i] = *(const short8*)&sA[(wm*64 + 16*i + rA)*40 + kg*8];
    #pragma unroll
    for (int j=0;j<4;j++) bf[j] = *(const short8*)&sB[(wn*64 + 16*j + rA)*40 + kg*8];
    #pragma unroll
    for (int i=0;i<4;i++)
      #pragma unroll
      for (int j=0;j<4;j++)
        acc[i][j] = __builtin_amdgcn_mfma_f32_16x16x32_bf16(af[i], bf[j], acc[i][j], 0, 0, 0);
  }
  #pragma unroll
  for (int i=0;i<4;i++){
    int rb = m0 + wm*64 + 16*i + kg*4;
    #pragma unroll
    for (int j=0;j<4;j++){
      int cc = n0 + wn*64 + 16*j + rA;
      float bv = bih[cc] + bhh[cc];
      float sc = (cc < 512) ? NL2E : NL2E2;
      #pragma unroll
      for (int rg=0;rg<4;rg++)
        XP[(size_t)(rb+rg)*768 + cc] = (acc[i][j][rg] + bv) * sc;
    }
  }
}

// ---------------- GRU recurrence: int8 MFMA (K=64), one WG per chain ----------------
// R11 winner byte-for-byte (serial schedule: the R12-R15 fusion experiments showed
// concurrent whole-chip GEMM drops boost clocks for the latency-critical recurrence —
// co-residency was exonerated by the 84480B-LDS 1-block/CU A/B in R15).
__global__ __launch_bounds__(512,2)
void gru_k(const float* __restrict__ xp, const float* __restrict__ Whh,
           char* __restrict__ hs8){
  int b = blockIdx.x;
  int tid = threadIdx.x;
  int wave = tid >> 6, lane = tid & 63;
  int rA = lane & 15, kg = lane >> 4;
  int ua = 32*wave + rA;                       // unit a; unit b = ua + 16
  __shared__ __align__(16) char h_q[2][256];   // int8 h, double-buffered by parity

  const float NL2E  = -1.4426950408889634f;
  const float NL2E2 = -2.8853900817779268f;

  // ---- startup: per-row int8 quantization of W_hh into register B-fragments ----
  i32x4 bw[3][2][4];
  float dsc[3][2];                             // dequant scale, exp2 factor folded in
  #pragma unroll
  for (int g=0; g<3; g++){
    #pragma unroll
    for (int hh=0; hh<2; hh++){
      const float* rp = Whh + (size_t)(g*256 + 32*wave + hh*16 + rA)*256 + kg*16;
      float mx = 0.f;
      #pragma unroll
      for (int kk=0; kk<4; kk++)
        #pragma unroll
        for (int j=0; j<16; j++)
          mx = fmaxf(mx, fabsf(rp[kk*64 + j]));
      mx = fmaxf(mx, __shfl_xor(mx, 16, 64));  // reduce across kg groups (same rA)
      mx = fmaxf(mx, __shfl_xor(mx, 32, 64));
      mx = fmaxf(mx, 1e-20f);
      float s = 127.f / mx;
      float fold = (g == 2) ? NL2E2 : NL2E;
      dsc[g][hh] = mx * (1.f/(127.f*127.f)) * fold;
      #pragma unroll
      for (int kk=0; kk<4; kk++){
        i32x4 v;
        #pragma unroll
        for (int q=0; q<4; q++){
          const float* pp = rp + kk*64 + q*4;
          int q0 = __float2int_rn(pp[0]*s) & 255;
          int q1 = __float2int_rn(pp[1]*s) & 255;
          int q2 = __float2int_rn(pp[2]*s) & 255;
          int q3 = __float2int_rn(pp[3]*s) & 255;
          v[q] = q0 | (q1<<8) | (q2<<16) | (q3<<24);
        }
        bw[g][hh][kk] = v;
      }
    }
  }
  if (tid < 256) h_q[0][tid] = 0;
  __syncthreads();

  // ---- xp prefetch registers, depth 2 (XP already prescaled) ----
  float xa[2][3], xb[2][3];
  {
    const float* q0 = xp + (size_t)b*768;
    const float* q1 = xp + (size_t)(16 + b)*768;
    #pragma unroll
    for (int g=0; g<3; g++){
      xa[0][g] = q0[g*256 + ua];  xb[0][g] = q0[g*256 + ua + 16];
      xa[1][g] = q1[g*256 + ua];  xb[1][g] = q1[g*256 + ua + 16];
    }
  }
  float ha = 0.f, hb = 0.f;                    // fp32 carried state (2 units/lane)
  const float* pA = xp + (size_t)(2*16 + b)*768 + ua;   // refill src (row T+2), +12288/half
  char* ph = hs8 + (size_t)b*256 + ua;                  // hs store, +4096/half

#define GRU_HALF(half, DO_REFILL)                                                        \
  {                                                                                      \
    i32x4 a[4];                                                                          \
    _Pragma("unroll")                                                                    \
    for (int kk=0; kk<4; kk++)                                                           \
      a[kk] = *(const i32x4*)&h_q[half][kk*64 + kg*16];                                  \
    i32x4 a00={}, a01={}, a10={}, a11={}, a20={}, a21={};                                \
    __builtin_amdgcn_s_setprio(1);                                                       \
    _Pragma("unroll")                                                                    \
    for (int kk=0; kk<4; kk++){                                                          \
      a00 = __builtin_amdgcn_mfma_i32_16x16x64_i8(a[kk], bw[0][0][kk], a00, 0,0,0);      \
      a01 = __builtin_amdgcn_mfma_i32_16x16x64_i8(a[kk], bw[0][1][kk], a01, 0,0,0);      \
      a10 = __builtin_amdgcn_mfma_i32_16x16x64_i8(a[kk], bw[1][0][kk], a10, 0,0,0);      \
      a11 = __builtin_amdgcn_mfma_i32_16x16x64_i8(a[kk], bw[1][1][kk], a11, 0,0,0);      \
      a20 = __builtin_amdgcn_mfma_i32_16x16x64_i8(a[kk], bw[2][0][kk], a20, 0,0,0);      \
      a21 = __builtin_amdgcn_mfma_i32_16x16x64_i8(a[kk], bw[2][1][kk], a21, 0,0,0);      \
    }                                                                                    \
    __builtin_amdgcn_s_setprio(0);                                                       \
    float ra = __builtin_amdgcn_rcpf(1.f + __builtin_amdgcn_exp2f(fmaf((float)a00[0], dsc[0][0], xa[half][0]))); \
    float rb = __builtin_amdgcn_rcpf(1.f + __builtin_amdgcn_exp2f(fmaf((float)a01[0], dsc[0][1], xb[half][0]))); \
    float za = __builtin_amdgcn_rcpf(1.f + __builtin_amdgcn_exp2f(fmaf((float)a10[0], dsc[1][0], xa[half][1]))); \
    float zb = __builtin_amdgcn_rcpf(1.f + __builtin_amdgcn_exp2f(fmaf((float)a11[0], dsc[1][1], xb[half][1]))); \
    float na = fmaf(2.f, __builtin_amdgcn_rcpf(1.f + __builtin_amdgcn_exp2f(             \
                 fmaf(ra, (float)a20[0]*dsc[2][0], xa[half][2]))), -1.f);                \
    float nb = fmaf(2.f, __builtin_amdgcn_rcpf(1.f + __builtin_amdgcn_exp2f(             \
                 fmaf(rb, (float)a21[0]*dsc[2][1], xb[half][2]))), -1.f);                \
    ha = fmaf(za, ha - na, na);                                                          \
    hb = fmaf(zb, hb - nb, nb);                                                          \
    int qa = __float2int_rn(ha*127.f), qb = __float2int_rn(hb*127.f);                    \
    if (kg == 0){                                                                        \
      h_q[half^1][ua]    = (char)qa;                                                     \
      h_q[half^1][ua+16] = (char)qb;                                                     \
    }                                                                                    \
    if (kg == 1){                                                                        \
      ph[0]  = (char)qa;                                                                 \
      ph[16] = (char)qb;                                                                 \
    }                                                                                    \
    ph += 4096;                                                                          \
    if (DO_REFILL){                                                                      \
      xa[half][0] = pA[0];  xa[half][1] = pA[256]; xa[half][2] = pA[512];                \
      xb[half][0] = pA[16]; xb[half][1] = pA[272]; xb[half][2] = pA[528];                \
      pA += 12288;                                                                       \
    }                                                                                    \
    __builtin_amdgcn_sched_barrier(0);                                                   \
    asm volatile("s_waitcnt lgkmcnt(0)" ::: "memory");                                   \
    __builtin_amdgcn_s_barrier();                                                        \
    __builtin_amdgcn_sched_barrier(0);                                                   \
  }

  for (int t = 0; t < NSTEP-2; t += 2){
    GRU_HALF(0, 1)
    GRU_HALF(1, 1)
  }
  GRU_HALF(0, 0)
  GRU_HALF(1, 0)
#undef GRU_HALF
}

// ---------------- head: relu(h) @ W_out^T + b_out, softmax, outputs, task bins ----------------
// hs is int8 (scale 1/127, folded into sW). relu = max(q,0).
__global__ __launch_bounds__(256,1)
void head_k(const char* __restrict__ hs8, const float* __restrict__ Wout,
            const float* __restrict__ bout, const int* __restrict__ task,
            float* __restrict__ out, float* __restrict__ sums, float* __restrict__ counts){
  __shared__ float sW[1024];
  __shared__ float sbin[8], scnt[8];
  int tid = threadIdx.x;
  for (int i = tid; i < 1024; i += 256) sW[i] = Wout[i] * (1.f/127.f);
  if (tid < 8){ sbin[tid] = 0.f; scnt[tid] = 0.f; }
  __syncthreads();
  int rowi = blockIdx.x*256 + tid;   // 32768 rows total
  const uint4* hp = (const uint4*)(hs8 + (size_t)rowi*256);
  float l0 = bout[0], l1 = bout[1], l2 = bout[2], l3 = bout[3];
  #pragma unroll 4
  for (int c = 0; c < 16; c++){
    uint4 v = hp[c];
    uint arr[4] = {v.x, v.y, v.z, v.w};
    #pragma unroll
    for (int q = 0; q < 4; q++){
      uint w = arr[q];
      int k = c*16 + q*4;
      float h0 = (float)max((int)(char)(w      ), 0);
      float h1 = (float)max((int)(char)(w >>  8), 0);
      float h2 = (float)max((int)(char)(w >> 16), 0);
      float h3 = (float)max((int)(w) >> 24,       0);
      l0 = fmaf(h0, sW[k],     l0); l0 = fmaf(h1, sW[k+1],     l0);
      l0 = fmaf(h2, sW[k+2],   l0); l0 = fmaf(h3, sW[k+3],     l0);
      l1 = fmaf(h0, sW[256+k], l1); l1 = fmaf(h1, sW[257+k],   l1);
      l1 = fmaf(h2, sW[258+k], l1); l1 = fmaf(h3, sW[259+k],   l1);
      l2 = fmaf(h0, sW[512+k], l2); l2 = fmaf(h1, sW[513+k],   l2);
      l2 = fmaf(h2, sW[514+k], l2); l2 = fmaf(h3, sW[515+k],   l2);
      l3 = fmaf(h0, sW[768+k], l3); l3 = fmaf(h1, sW[769+k],   l3);
      l3 = fmaf(h2, sW[770+k], l3); l3 = fmaf(h3, sW[771+k],   l3);
    }
  }
  float mx = fmaxf(fmaxf(l0,l1), fmaxf(l2,l3));
  float e0 = __expf(l0-mx), e1 = __expf(l1-mx), e2 = __expf(l2-mx), e3 = __expf(l3-mx);
  float inv = 1.f/(e0+e1+e2+e3);
  float p0 = e0*inv, p1 = e1*inv, p2 = e2*inv, p3 = e3*inv;
  size_t o = (size_t)rowi*4;
  out[o+0]=p0; out[o+1]=p1; out[o+2]=p2; out[o+3]=p3;
  out[131072+o+0]=p0; out[131072+o+1]=p1; out[131072+o+2]=p2; out[131072+o+3]=p3;
  out[262144+o+0]=0.f; out[262144+o+1]=1.f; out[262144+o+2]=2.f; out[262144+o+3]=3.f;
  float loss = 256.f*p0 + 512.f*p1 + 1024.f*p2 + 2048.f*p3;
  int tk = task[rowi] & 7;
  atomicAdd(&sbin[tk], loss);
  atomicAdd(&scnt[tk], 1.f);
  __syncthreads();
  if (tid < 8){
    atomicAdd(&sums[tid], sbin[tid]);
    atomicAdd(&counts[tid], scnt[tid]);
  }
}

__global__ void fin_k(const float* __restrict__ sums, const float* __restrict__ counts,
                      float* __restrict__ o3){
  int i = threadIdx.x;
  if (i < 8){ float c = counts[i]; o3[i] = c > 0.f ? sums[i]/c : 0.f; }
}

extern "C" void kernel_launch(void* const* d_in, const int* in_sizes, int n_in,
                              void* d_out, int out_size, void* d_ws, size_t ws_size,
                              hipStream_t stream){
  const float* x    = (const float*)d_in[0];
  const int*   task = (const int*)d_in[1];
  const float* Wih  = (const float*)d_in[2];
  const float* Whh  = (const float*)d_in[3];
  const float* bih  = (const float*)d_in[4];
  const float* bhh  = (const float*)d_in[5];
  const float* Wout = (const float*)d_in[6];
  const float* bout = (const float*)d_in[7];
  float* out = (float*)d_out;
  char* ws = (char*)d_ws;
  float* xp    = (float*)ws;                                 // 100,663,296 B
  char* hs8    = (char*)(ws + 100663296);                    // 8,388,608 B (int8 h)
  float* sums  = (float*)(ws + 109051904);                   // 32 B
  float* counts= (float*)(ws + 109051936);                   // 32 B

  hipMemsetAsync(sums, 0, 64, stream);

  gemm_xp_k<<<1536, 256, 0, stream>>>(x, Wih, bih, bhh, xp);
  gru_k<<<16, 512, 0, stream>>>(xp, Whh, hs8);
  head_k<<<128, 256, 0, stream>>>(hs8, Wout, bout, task, out, sums, counts);
  fin_k<<<1, 64, 0, stream>>>(sums, counts, out + 393216);
}

// Round 17
// 1366.287 us; speedup vs baseline: 1.2775x; 1.0257x over previous
//
#include <hip/hip_runtime.h>

#define NSTEP 2048

typedef __attribute__((ext_vector_type(8))) short short8;
typedef __attribute__((ext_vector_type(4))) float f32x4;
typedef __attribute__((ext_vector_type(4))) int i32x4;

static __device__ __forceinline__ unsigned short f2bf(float f){
  unsigned u = __builtin_bit_cast(unsigned, f);
  u += 0x7FFFu + ((u >> 16) & 1u);   // RNE
  return (unsigned short)(u >> 16);
}

// ---------------- fp32 -> bf16 (for W_ih) ----------------
__global__ __launch_bounds__(256,1)
void cvt_bf16_k(const float* __restrict__ in, unsigned short* __restrict__ out, int n4){
  int i = blockIdx.x*256 + threadIdx.x;
  if (i < n4){
    f32x4 v = *(const f32x4*)(in + (size_t)i*4);
    ushort4 o; o.x=f2bf(v.x); o.y=f2bf(v.y); o.z=f2bf(v.z); o.w=f2bf(v.w);
    *(ushort4*)(out + (size_t)i*4) = o;
  }
}

// ---------------- xp = (x @ W_ih^T + b_ih + b_hh) * exp2-prescale ----------------
// Columns 0-511 (r,z) scaled by -log2(e); 512-767 (n) by -2log2(e). Scaling lives in
// the GEMM epilogue so the GRU refill stays raw loads (R8/R9 lesson).
__global__ __launch_bounds__(256,1)
void gemm_xp_k(const float* __restrict__ X, const unsigned short* __restrict__ Wb,
               const float* __restrict__ bih, const float* __restrict__ bhh,
               float* __restrict__ XP){
  __shared__ __align__(16) unsigned short sA[128*40];
  __shared__ __align__(16) unsigned short sB[128*40];
  const float NL2E  = -1.4426950408889634f;
  const float NL2E2 = -2.8853900817779268f;
  int bid = blockIdx.x;
  int xcd = bid & 7, loc = bid >> 3;          // 1536 = 8 * 192
  int mt = xcd*32 + loc/6;
  int nt = loc % 6;
  int m0 = mt*128, n0 = nt*128;
  int tid = threadIdx.x;
  int lane = tid & 63, wave = tid >> 6;
  int wm = wave >> 1, wn = wave & 1;
  int rA = lane & 15, kg = lane >> 4;
  f32x4 acc[4][4] = {};
  for (int k0 = 0; k0 < 1024; k0 += 32){
    __syncthreads();
    #pragma unroll
    for (int q = 0; q < 4; q++){
      int idx = tid + q*256;
      int r = idx >> 3, c4 = idx & 7;
      f32x4 v = *(const f32x4*)(X + (size_t)(m0+r)*1024 + k0 + c4*4);
      ushort4 o; o.x=f2bf(v.x); o.y=f2bf(v.y); o.z=f2bf(v.z); o.w=f2bf(v.w);
      *(ushort4*)&sA[r*40 + c4*4] = o;
    }
    #pragma unroll
    for (int q = 0; q < 2; q++){
      int idx = tid + q*256;
      int n = idx >> 2, c8 = idx & 3;
      uint4 v = *(const uint4*)(Wb + (size_t)(n0+n)*1024 + k0 + c8*8);
      *(uint4*)&sB[n*40 + c8*8] = v;
    }
    __syncthreads();
    short8 af[4], bf[4];
    #pragma unroll
    for (int i=0;i<4;i++) af[i] = *(const short8*)&sA[(wm*64 + 16*i + rA)*40 + kg*8];
    #pragma unroll
    for (int j=0;j<4;j++) bf[j] = *(const short8*)&sB[(wn*64 + 16*j + rA)*40 + kg*8];
    #pragma unroll
    for (int i=0;i<4;i++)
      #pragma unroll
      for (int j=0;j<4;j++)
        acc[i][j] = __builtin_amdgcn_mfma_f32_16x16x32_bf16(af[i], bf[j], acc[i][j], 0, 0, 0);
  }
  #pragma unroll
  for (int i=0;i<4;i++){
    int rb = m0 + wm*64 + 16*i + kg*4;
    #pragma unroll
    for (int j=0;j<4;j++){
      int cc = n0 + wn*64 + 16*j + rA;
      float bv = bih[cc] + bhh[cc];
      float sc = (cc < 512) ? NL2E : NL2E2;
      #pragma unroll
      for (int rg=0;rg<4;rg++)
        XP[(size_t)(rb+rg)*768 + cc] = (acc[i][j][rg] + bv) * sc;
    }
  }
}

// ---------------- GRU recurrence: int8 MFMA (K=64), one WG per chain ----------------
// Best-measured structure (R11). One fenced raw barrier per step; h int8 double-buffered
// by parity; W_hh in registers as i8 B-fragments (per-row scales, exact i32 K=256 dot);
// gates in-register via exp2 (factors pre-folded into XP and dsc); running per-lane
// pointers; depth-2 raw xp prefetch (never any load->VALU dep before the barrier).
__global__ __launch_bounds__(512,2)
void gru_k(const float* __restrict__ xp, const float* __restrict__ Whh,
           char* __restrict__ hs8){
  int b = blockIdx.x;
  int tid = threadIdx.x;
  int wave = tid >> 6, lane = tid & 63;
  int rA = lane & 15, kg = lane >> 4;
  int ua = 32*wave + rA;                       // unit a; unit b = ua + 16
  __shared__ __align__(16) char h_q[2][256];   // int8 h, double-buffered by parity

  const float NL2E  = -1.4426950408889634f;
  const float NL2E2 = -2.8853900817779268f;

  // ---- startup: per-row int8 quantization of W_hh into register B-fragments ----
  i32x4 bw[3][2][4];
  float dsc[3][2];                             // dequant scale, exp2 factor folded in
  #pragma unroll
  for (int g=0; g<3; g++){
    #pragma unroll
    for (int hh=0; hh<2; hh++){
      const float* rp = Whh + (size_t)(g*256 + 32*wave + hh*16 + rA)*256 + kg*16;
      float mx = 0.f;
      #pragma unroll
      for (int kk=0; kk<4; kk++)
        #pragma unroll
        for (int j=0; j<16; j++)
          mx = fmaxf(mx, fabsf(rp[kk*64 + j]));
      mx = fmaxf(mx, __shfl_xor(mx, 16, 64));  // reduce across kg groups (same rA)
      mx = fmaxf(mx, __shfl_xor(mx, 32, 64));
      mx = fmaxf(mx, 1e-20f);
      float s = 127.f / mx;
      float fold = (g == 2) ? NL2E2 : NL2E;
      dsc[g][hh] = mx * (1.f/(127.f*127.f)) * fold;
      #pragma unroll
      for (int kk=0; kk<4; kk++){
        i32x4 v;
        #pragma unroll
        for (int q=0; q<4; q++){
          const float* pp = rp + kk*64 + q*4;
          int q0 = __float2int_rn(pp[0]*s) & 255;
          int q1 = __float2int_rn(pp[1]*s) & 255;
          int q2 = __float2int_rn(pp[2]*s) & 255;
          int q3 = __float2int_rn(pp[3]*s) & 255;
          v[q] = q0 | (q1<<8) | (q2<<16) | (q3<<24);
        }
        bw[g][hh][kk] = v;
      }
    }
  }
  if (tid < 256) h_q[0][tid] = 0;
  __syncthreads();

  // ---- xp prefetch registers, depth 2 (XP already prescaled) ----
  float xa[2][3], xb[2][3];
  {
    const float* q0 = xp + (size_t)b*768;
    const float* q1 = xp + (size_t)(16 + b)*768;
    #pragma unroll
    for (int g=0; g<3; g++){
      xa[0][g] = q0[g*256 + ua];  xb[0][g] = q0[g*256 + ua + 16];
      xa[1][g] = q1[g*256 + ua];  xb[1][g] = q1[g*256 + ua + 16];
    }
  }
  float ha = 0.f, hb = 0.f;                    // fp32 carried state (2 units/lane)
  const float* pA = xp + (size_t)(2*16 + b)*768 + ua;   // refill src (row T+2), +12288/half
  char* ph = hs8 + (size_t)b*256 + ua;                  // hs store, +4096/half

#define GRU_HALF(half, DO_REFILL)                                                        \
  {                                                                                      \
    i32x4 a[4];                                                                          \
    _Pragma("unroll")                                                                    \
    for (int kk=0; kk<4; kk++)                                                           \
      a[kk] = *(const i32x4*)&h_q[half][kk*64 + kg*16];                                  \
    i32x4 a00={}, a01={}, a10={}, a11={}, a20={}, a21={};                                \
    __builtin_amdgcn_s_setprio(1);                                                       \
    _Pragma("unroll")                                                                    \
    for (int kk=0; kk<4; kk++){                                                          \
      a00 = __builtin_amdgcn_mfma_i32_16x16x64_i8(a[kk], bw[0][0][kk], a00, 0,0,0);      \
      a01 = __builtin_amdgcn_mfma_i32_16x16x64_i8(a[kk], bw[0][1][kk], a01, 0,0,0);      \
      a10 = __builtin_amdgcn_mfma_i32_16x16x64_i8(a[kk], bw[1][0][kk], a10, 0,0,0);      \
      a11 = __builtin_amdgcn_mfma_i32_16x16x64_i8(a[kk], bw[1][1][kk], a11, 0,0,0);      \
      a20 = __builtin_amdgcn_mfma_i32_16x16x64_i8(a[kk], bw[2][0][kk], a20, 0,0,0);      \
      a21 = __builtin_amdgcn_mfma_i32_16x16x64_i8(a[kk], bw[2][1][kk], a21, 0,0,0);      \
    }                                                                                    \
    __builtin_amdgcn_s_setprio(0);                                                       \
    float ra = __builtin_amdgcn_rcpf(1.f + __builtin_amdgcn_exp2f(fmaf((float)a00[0], dsc[0][0], xa[half][0]))); \
    float rb = __builtin_amdgcn_rcpf(1.f + __builtin_amdgcn_exp2f(fmaf((float)a01[0], dsc[0][1], xb[half][0]))); \
    float za = __builtin_amdgcn_rcpf(1.f + __builtin_amdgcn_exp2f(fmaf((float)a10[0], dsc[1][0], xa[half][1]))); \
    float zb = __builtin_amdgcn_rcpf(1.f + __builtin_amdgcn_exp2f(fmaf((float)a11[0], dsc[1][1], xb[half][1]))); \
    float na = fmaf(2.f, __builtin_amdgcn_rcpf(1.f + __builtin_amdgcn_exp2f(             \
                 fmaf(ra, (float)a20[0]*dsc[2][0], xa[half][2]))), -1.f);                \
    float nb = fmaf(2.f, __builtin_amdgcn_rcpf(1.f + __builtin_amdgcn_exp2f(             \
                 fmaf(rb, (float)a21[0]*dsc[2][1], xb[half][2]))), -1.f);                \
    ha = fmaf(za, ha - na, na);                                                          \
    hb = fmaf(zb, hb - nb, nb);                                                          \
    int qa = __float2int_rn(ha*127.f), qb = __float2int_rn(hb*127.f);                    \
    if (kg == 0){                                                                        \
      h_q[half^1][ua]    = (char)qa;                                                     \
      h_q[half^1][ua+16] = (char)qb;                                                     \
    }                                                                                    \
    if (kg == 1){                                                                        \
      ph[0]  = (char)qa;                                                                 \
      ph[16] = (char)qb;                                                                 \
    }                                                                                    \
    ph += 4096;                                                                          \
    if (DO_REFILL){                                                                      \
      xa[half][0] = pA[0];  xa[half][1] = pA[256]; xa[half][2] = pA[512];                \
      xb[half][0] = pA[16]; xb[half][1] = pA[272]; xb[half][2] = pA[528];                \
      pA += 12288;                                                                       \
    }                                                                                    \
    __builtin_amdgcn_sched_barrier(0);                                                   \
    asm volatile("s_waitcnt lgkmcnt(0)" ::: "memory");                                   \
    __builtin_amdgcn_s_barrier();                                                        \
    __builtin_amdgcn_sched_barrier(0);                                                   \
  }

  for (int t = 0; t < NSTEP-2; t += 2){
    GRU_HALF(0, 1)
    GRU_HALF(1, 1)
  }
  GRU_HALF(0, 0)
  GRU_HALF(1, 0)
#undef GRU_HALF
}

// ---------------- head: relu(h) @ W_out^T + b_out, softmax, outputs, task bins ----------------
// hs is int8 (scale 1/127, folded into sW). relu = max(q,0).
__global__ __launch_bounds__(256,1)
void head_k(const char* __restrict__ hs8, const float* __restrict__ Wout,
            const float* __restrict__ bout, const int* __restrict__ task,
            float* __restrict__ out, float* __restrict__ sums, float* __restrict__ counts){
  __shared__ float sW[1024];
  __shared__ float sbin[8], scnt[8];
  int tid = threadIdx.x;
  for (int i = tid; i < 1024; i += 256) sW[i] = Wout[i] * (1.f/127.f);
  if (tid < 8){ sbin[tid] = 0.f; scnt[tid] = 0.f; }
  __syncthreads();
  int rowi = blockIdx.x*256 + tid;   // 32768 rows total
  const uint4* hp = (const uint4*)(hs8 + (size_t)rowi*256);
  float l0 = bout[0], l1 = bout[1], l2 = bout[2], l3 = bout[3];
  #pragma unroll 4
  for (int c = 0; c < 16; c++){
    uint4 v = hp[c];
    uint arr[4] = {v.x, v.y, v.z, v.w};
    #pragma unroll
    for (int q = 0; q < 4; q++){
      uint w = arr[q];
      int k = c*16 + q*4;
      float h0 = (float)max((int)(char)(w      ), 0);
      float h1 = (float)max((int)(char)(w >>  8), 0);
      float h2 = (float)max((int)(char)(w >> 16), 0);
      float h3 = (float)max((int)(w) >> 24,       0);
      l0 = fmaf(h0, sW[k],     l0); l0 = fmaf(h1, sW[k+1],     l0);
      l0 = fmaf(h2, sW[k+2],   l0); l0 = fmaf(h3, sW[k+3],     l0);
      l1 = fmaf(h0, sW[256+k], l1); l1 = fmaf(h1, sW[257+k],   l1);
      l1 = fmaf(h2, sW[258+k], l1); l1 = fmaf(h3, sW[259+k],   l1);
      l2 = fmaf(h0, sW[512+k], l2); l2 = fmaf(h1, sW[513+k],   l2);
      l2 = fmaf(h2, sW[514+k], l2); l2 = fmaf(h3, sW[515+k],   l2);
      l3 = fmaf(h0, sW[768+k], l3); l3 = fmaf(h1, sW[769+k],   l3);
      l3 = fmaf(h2, sW[770+k], l3); l3 = fmaf(h3, sW[771+k],   l3);
    }
  }
  float mx = fmaxf(fmaxf(l0,l1), fmaxf(l2,l3));
  float e0 = __expf(l0-mx), e1 = __expf(l1-mx), e2 = __expf(l2-mx), e3 = __expf(l3-mx);
  float inv = 1.f/(e0+e1+e2+e3);
  float p0 = e0*inv, p1 = e1*inv, p2 = e2*inv, p3 = e3*inv;
  size_t o = (size_t)rowi*4;
  out[o+0]=p0; out[o+1]=p1; out[o+2]=p2; out[o+3]=p3;
  out[131072+o+0]=p0; out[131072+o+1]=p1; out[131072+o+2]=p2; out[131072+o+3]=p3;
  out[262144+o+0]=0.f; out[262144+o+1]=1.f; out[262144+o+2]=2.f; out[262144+o+3]=3.f;
  float loss = 256.f*p0 + 512.f*p1 + 1024.f*p2 + 2048.f*p3;
  int tk = task[rowi] & 7;
  atomicAdd(&sbin[tk], loss);
  atomicAdd(&scnt[tk], 1.f);
  __syncthreads();
  if (tid < 8){
    atomicAdd(&sums[tid], sbin[tid]);
    atomicAdd(&counts[tid], scnt[tid]);
  }
}

__global__ void fin_k(const float* __restrict__ sums, const float* __restrict__ counts,
                      float* __restrict__ o3){
  int i = threadIdx.x;
  if (i < 8){ float c = counts[i]; o3[i] = c > 0.f ? sums[i]/c : 0.f; }
}

extern "C" void kernel_launch(void* const* d_in, const int* in_sizes, int n_in,
                              void* d_out, int out_size, void* d_ws, size_t ws_size,
                              hipStream_t stream){
  const float* x    = (const float*)d_in[0];
  const int*   task = (const int*)d_in[1];
  const float* Wih  = (const float*)d_in[2];
  const float* Whh  = (const float*)d_in[3];
  const float* bih  = (const float*)d_in[4];
  const float* bhh  = (const float*)d_in[5];
  const float* Wout = (const float*)d_in[6];
  const float* bout = (const float*)d_in[7];
  float* out = (float*)d_out;
  char* ws = (char*)d_ws;
  unsigned short* wih_bf = (unsigned short*)ws;              // 1,572,864 B
  float* xp    = (float*)(ws + 1572864);                     // 100,663,296 B
  char* hs8    = (char*)(ws + 102236160);                    // 8,388,608 B (int8 h)
  float* sums  = (float*)(ws + 110624768);                   // 32 B
  float* counts= (float*)(ws + 110624800);                   // 32 B

  hipMemsetAsync(sums, 0, 64, stream);

  cvt_bf16_k<<<768, 256, 0, stream>>>(Wih, wih_bf, 196608);
  gemm_xp_k<<<1536, 256, 0, stream>>>(x, wih_bf, bih, bhh, xp);
  gru_k<<<16, 512, 0, stream>>>(xp, Whh, hs8);
  head_k<<<128, 256, 0, stream>>>(hs8, Wout, bout, task, out, sums, counts);
  fin_k<<<1, 64, 0, stream>>>(sums, counts, out + 393216);
}